// Round 4
// baseline (277.552 us; speedup 1.0000x reference)
//
#include <hip/hip_runtime.h>
#include <hip/hip_bf16.h>

#define N_ATOM 10000
#define N_EDGE 40000
#define DD 64
#define BOND_DIM 10
#define EPS_BN 1e-6f
#define EPS_SM 1e-8f

// ---- workspace layout (float indices) ----
constexpr size_t OFF_WP     = 0;                        // 4096*12 folded enc W (+bias+pad)
constexpr size_t OFF_ATTW   = OFF_WP + 4096 * 12;       // 4096
constexpr size_t OFF_ATTB   = OFF_ATTW + 4096;          // 64
constexpr size_t OFF_DENOM  = OFF_ATTB + 64;            // N_ATOM
constexpr size_t OFF_CTX    = OFF_DENOM + N_ATOM;       // N_ATOM*DD
// total 703,312 floats ~= 2.81 MB

// ---------- kernel 0: fold BN params into encoder / attention weights ----------
__global__ void fold_kernel(const float* enc_W, const float* enc_b,
                            const float* g1, const float* b1,
                            const float* m1, const float* v1,
                            const float* att_W, const float* att_b,
                            const float* g2, const float* b2v,
                            const float* m2, const float* v2,
                            float* ws) {
    int i = blockIdx.x * 256 + threadIdx.x;
    if (i < 4096) {
        float s = g1[i] * rsqrtf(v1[i] + EPS_BN);
        float t = b1[i] - m1[i] * s;
        float* row = ws + OFF_WP + (size_t)i * 12;
#pragma unroll
        for (int k = 0; k < BOND_DIM; k++) row[k] = enc_W[i * BOND_DIM + k] * s;
        row[10] = enc_b[i] * s + t;
        row[11] = 0.f;
    } else if (i < 8192) {
        int j = i - 4096;
        int f = j >> 6;
        float s = g2[f] * rsqrtf(v2[f] + EPS_BN);
        ws[OFF_ATTW + j] = att_W[j] * s;
    } else if (i < 8256) {
        int f = i - 8192;
        float s = g2[f] * rsqrtf(v2[f] + EPS_BN);
        ws[OFF_ATTB + f] = att_b[f] * s + b2v[f] - m2[f] * s;
    }
}

// ---------- kernel 1: fully fused per-edge pipeline ----------
// encoder GEMV + einsum + align score + exp + atend + segment-sum atomics.
// No max-shift: ratio sum(ex*atend)/(sum(ex)+eps) deviates from ref only via
// the eps term (rel ~1e-8); scores are O(+-1) so expf is safe in fp32.
// block = 256 threads (4 waves), 16 edges/block, 4 edges/wave, thread f = lane.
__global__ __launch_bounds__(256) void edge_kernel(
    const float* atom, const int* bidx, const float* bond,
    const float* alignW, const float* alignb,
    const float* ws, float* denom, float* ctx) {
    __shared__ float s_bond[16][BOND_DIM];
    __shared__ float s_atgt[16][DD];
    __shared__ float s_anbr[16][DD];
    __shared__ float s_nb[16][DD];
    __shared__ int s_tgt[16];

    const int t = threadIdx.x;
    const int lane = t & 63;
    const int wave = t >> 6;
    const int e0 = blockIdx.x * 16;

    if (t < 16) s_tgt[t] = bidx[2 * (e0 + t)];
    if (t < 160) {
        int le = t / BOND_DIM, k = t % BOND_DIM;
        s_bond[le][k] = bond[(size_t)(e0 + le) * BOND_DIM + k];
    }
    __syncthreads();
#pragma unroll
    for (int j = 0; j < 4; j++) {
        int le = wave * 4 + j;
        int nbr = bidx[2 * (e0 + le) + 1];
        s_atgt[le][lane] = atom[(size_t)s_tgt[le] * DD + lane];
        s_anbr[le][lane] = atom[(size_t)nbr * DD + lane];
    }
    __syncthreads();

    float bb[4][BOND_DIM];
#pragma unroll
    for (int j = 0; j < 4; j++)
#pragma unroll
        for (int k = 0; k < BOND_DIM; k++) bb[j][k] = s_bond[wave * 4 + j][k];

    // neighbor[f] = sum_d atom[nbr][d] * relu(bn1(bond @ encW.T))[d*64+f]
    float acc[4] = {0.f, 0.f, 0.f, 0.f};
    const float4* Wp4 = (const float4*)(ws + OFF_WP);
    for (int d = 0; d < DD; d++) {
        int row = d * DD + lane;
        float4 w0 = Wp4[row * 3 + 0];
        float4 w1 = Wp4[row * 3 + 1];
        float4 w2 = Wp4[row * 3 + 2];
        float wk[10] = {w0.x, w0.y, w0.z, w0.w, w1.x, w1.y, w1.z, w1.w, w2.x, w2.y};
        float bias = w2.z;
#pragma unroll
        for (int j = 0; j < 4; j++) {
            float v = bias;
#pragma unroll
            for (int k = 0; k < BOND_DIM; k++) v = fmaf(bb[j][k], wk[k], v);
            v = fmaxf(v, 0.f);
            acc[j] = fmaf(s_anbr[wave * 4 + j][d], v, acc[j]);
        }
    }
#pragma unroll
    for (int j = 0; j < 4; j++) s_nb[wave * 4 + j][lane] = acc[j];
    __syncthreads();

    const float aw1 = alignW[lane];
    const float aw2 = alignW[64 + lane];
    const float alb = alignb[0];
    const float* attW = ws + OFF_ATTW;
    const float ab = (ws + OFF_ATTB)[lane];

#pragma unroll
    for (int j = 0; j < 4; j++) {
        int le = wave * 4 + j;
        // align score: leaky_relu(dot([atom_tgt, neighbor], alignW) + b)
        float v = s_atgt[le][lane] * aw1 + s_nb[le][lane] * aw2;
#pragma unroll
        for (int off = 32; off > 0; off >>= 1) v += __shfl_xor(v, off);
        float sc = v + alb;
        sc = sc > 0.f ? sc : 0.01f * sc;  // leaky_relu slope 0.01
        float ex = expf(sc);

        // atend[f] = bn2(neighbor @ att_W.T + att_b)  (folded)
        float av = ab;
#pragma unroll 8
        for (int d = 0; d < DD; d++) av = fmaf(attW[lane * DD + d], s_nb[le][d], av);

        int tgt = s_tgt[le];
        atomicAdd(&ctx[(size_t)tgt * DD + lane], ex * av);
        if (lane == 0) atomicAdd(&denom[tgt], ex);
    }
}

// ---------- kernel 2: context finalize (elu) + GRU cell ----------
// 4 atoms per block: each thread's weight rows (float4-vectorized) reused 4x.
__global__ __launch_bounds__(192) void gru_kernel(
    const float* atom, const float* denom, const float* ctx,
    const float* Wih, const float* Whh,
    const float* bih, const float* bhh,
    float* out) {
    __shared__ float sctx[4][DD];
    __shared__ float satom[4][DD];
    __shared__ float sgi[4][192];
    __shared__ float sgh[4][192];
    const int a0 = blockIdx.x * 4;
    const int t = threadIdx.x;

    for (int idx = t; idx < 256; idx += 192) {
        int a = idx >> 6, f = idx & 63;
        float c = ctx[(size_t)(a0 + a) * DD + f] / (denom[a0 + a] + EPS_SM);
        sctx[a][f] = c > 0.f ? c : expm1f(c);  // elu
        satom[a][f] = atom[(size_t)(a0 + a) * DD + f];
    }
    __syncthreads();

    const float4* Wi4 = (const float4*)Wih + (size_t)t * 16;
    const float4* Wh4 = (const float4*)Whh + (size_t)t * 16;
    const float bi = bih[t], bh = bhh[t];
    float gi[4] = {bi, bi, bi, bi};
    float gh[4] = {bh, bh, bh, bh};
#pragma unroll 4
    for (int q = 0; q < 16; q++) {
        float4 wi = Wi4[q];
        float4 wh = Wh4[q];
#pragma unroll
        for (int a = 0; a < 4; a++) {
            const float* c = &sctx[a][q * 4];
            const float* h = &satom[a][q * 4];
            gi[a] = fmaf(wi.x, c[0], gi[a]);
            gi[a] = fmaf(wi.y, c[1], gi[a]);
            gi[a] = fmaf(wi.z, c[2], gi[a]);
            gi[a] = fmaf(wi.w, c[3], gi[a]);
            gh[a] = fmaf(wh.x, h[0], gh[a]);
            gh[a] = fmaf(wh.y, h[1], gh[a]);
            gh[a] = fmaf(wh.z, h[2], gh[a]);
            gh[a] = fmaf(wh.w, h[3], gh[a]);
        }
    }
#pragma unroll
    for (int a = 0; a < 4; a++) { sgi[a][t] = gi[a]; sgh[a][t] = gh[a]; }
    __syncthreads();

    for (int idx = t; idx < 256; idx += 192) {
        int a = idx >> 6, f = idx & 63;
        float r = 1.f / (1.f + expf(-(sgi[a][f] + sgh[a][f])));
        float z = 1.f / (1.f + expf(-(sgi[a][64 + f] + sgh[a][64 + f])));
        float n = tanhf(sgi[a][128 + f] + r * sgh[a][128 + f]);
        out[(size_t)(a0 + a) * DD + f] = (1.f - z) * n + z * satom[a][f];
    }
}

extern "C" void kernel_launch(void* const* d_in, const int* in_sizes, int n_in,
                              void* d_out, int out_size, void* d_ws, size_t ws_size,
                              hipStream_t stream) {
    const float* atom   = (const float*)d_in[0];
    const int*   bidx   = (const int*)d_in[1];
    const float* bond   = (const float*)d_in[2];
    const float* enc_W  = (const float*)d_in[3];
    const float* enc_b  = (const float*)d_in[4];
    const float* bn1_g  = (const float*)d_in[5];
    const float* bn1_b  = (const float*)d_in[6];
    const float* bn1_m  = (const float*)d_in[7];
    const float* bn1_v  = (const float*)d_in[8];
    const float* alignW = (const float*)d_in[9];
    const float* alignb = (const float*)d_in[10];
    const float* att_W  = (const float*)d_in[11];
    const float* att_b  = (const float*)d_in[12];
    const float* bn2_g  = (const float*)d_in[13];
    const float* bn2_b  = (const float*)d_in[14];
    const float* bn2_m  = (const float*)d_in[15];
    const float* bn2_v  = (const float*)d_in[16];
    const float* gWih   = (const float*)d_in[17];
    const float* gWhh   = (const float*)d_in[18];
    const float* gbih   = (const float*)d_in[19];
    const float* gbhh   = (const float*)d_in[20];

    float* ws  = (float*)d_ws;
    float* out = (float*)d_out;   // reference output dtype is float32

    // zero denom + ctx accumulators (contiguous region)
    hipMemsetAsync(ws + OFF_DENOM, 0, (size_t)(N_ATOM + (size_t)N_ATOM * DD) * 4, stream);

    fold_kernel<<<33, 256, 0, stream>>>(enc_W, enc_b, bn1_g, bn1_b, bn1_m, bn1_v,
                                        att_W, att_b, bn2_g, bn2_b, bn2_m, bn2_v, ws);

    edge_kernel<<<N_EDGE / 16, 256, 0, stream>>>(
        atom, bidx, bond, alignW, alignb, ws,
        ws + OFF_DENOM, ws + OFF_CTX);

    gru_kernel<<<N_ATOM / 4, 192, 0, stream>>>(atom, ws + OFF_DENOM, ws + OFF_CTX,
                                               gWih, gWhh, gbih, gbhh, out);
}

// Round 5
// 202.043 us; speedup vs baseline: 1.3737x; 1.3737x over previous
//
#include <hip/hip_runtime.h>

#define N_ATOM 10000
#define N_EDGE 40000
#define DD 64
#define BOND_DIM 10
#define EPS_BN 1e-6f
#define EPS_SM 1e-8f
#define EPB 32   // edges per block
#define EPW 8    // edges per wave
#define GA 8     // atoms per GRU block

// ---- workspace layout (float indices) ----
constexpr size_t OFF_WKP   = 0;                       // 11 planes x 4096 (k-major folded enc W, plane10 = bias)
constexpr size_t OFF_ATTWT = OFF_WKP + 11 * 4096;     // 4096  attWT[d*64+f] = folded attW[f,d]
constexpr size_t OFF_ATTB  = OFF_ATTWT + 4096;        // 64
constexpr size_t OFF_WIHT  = OFF_ATTB + 64;           // 12288 WihT[d*192+t]
constexpr size_t OFF_WHHT  = OFF_WIHT + 12288;        // 12288
constexpr size_t OFF_DENOM = OFF_WHHT + 12288;        // N_ATOM
constexpr size_t OFF_CTX   = OFF_DENOM + N_ATOM;      // N_ATOM*DD
// total 723,792 floats ~= 2.90 MB (round-4 proved ws >= 2.81 MB; +98KB assumed OK)

// ---------- kernel 0: fold BN into weights + build transposed layouts ----------
__global__ void fold_kernel(const float* enc_W, const float* enc_b,
                            const float* g1, const float* b1,
                            const float* m1, const float* v1,
                            const float* att_W, const float* att_b,
                            const float* g2, const float* b2v,
                            const float* m2, const float* v2,
                            const float* Wih, const float* Whh,
                            float* ws) {
    int i = blockIdx.x * 256 + threadIdx.x;
    if (i < 4096) {
        // k-major folded encoder weights: plane k, row i
        float s = g1[i] * rsqrtf(v1[i] + EPS_BN);
        float t = b1[i] - m1[i] * s;
#pragma unroll
        for (int k = 0; k < BOND_DIM; k++)
            ws[OFF_WKP + (size_t)k * 4096 + i] = enc_W[i * BOND_DIM + k] * s;
        ws[OFF_WKP + (size_t)10 * 4096 + i] = enc_b[i] * s + t;
    } else if (i < 8192) {
        // transposed folded attention weight: attWT[d*64+f] = att_W[f*64+d]*s2(f)
        int j = i - 4096;
        int d = j >> 6, f = j & 63;
        float s = g2[f] * rsqrtf(v2[f] + EPS_BN);
        ws[OFF_ATTWT + j] = att_W[f * DD + d] * s;
    } else if (i < 8256) {
        int f = i - 8192;
        float s = g2[f] * rsqrtf(v2[f] + EPS_BN);
        ws[OFF_ATTB + f] = att_b[f] * s + b2v[f] - m2[f] * s;
    } else if (i < 8256 + 12288) {
        int j = i - 8256;
        int d = j / 192, t = j % 192;
        ws[OFF_WIHT + j] = Wih[t * DD + d];
    } else if (i < 8256 + 24576) {
        int j = i - 8256 - 12288;
        int d = j / 192, t = j % 192;
        ws[OFF_WHHT + j] = Whh[t * DD + d];
    }
}

// ---------- kernel 1: fused per-edge pipeline ----------
// 256 threads = 4 waves; 8 edges/wave; thread f = lane. All weight loads coalesced.
__global__ __launch_bounds__(256) void edge_kernel(
    const float* atom, const int* bidx, const float* bond,
    const float* alignW, const float* alignb,
    const float* ws, float* denom, float* ctx) {
    __shared__ float s_bond[EPB][BOND_DIM];
    __shared__ float s_anbr[EPB][DD];
    __shared__ float s_nb[EPB][DD];
    __shared__ int s_tgt[EPB];

    const int t = threadIdx.x;
    const int lane = t & 63;
    const int wave = t >> 6;
    const int e0 = blockIdx.x * EPB;

    if (t < EPB) s_tgt[t] = bidx[2 * (e0 + t)];
    for (int idx = t; idx < EPB * BOND_DIM; idx += 256)
        s_bond[idx / BOND_DIM][idx % BOND_DIM] = bond[(size_t)e0 * BOND_DIM + idx];
    __syncthreads();

    // neighbor atom rows -> LDS (coalesced, 256B per edge)
#pragma unroll
    for (int j = 0; j < EPW; j++) {
        int le = wave * EPW + j;
        int nbr = bidx[2 * (e0 + le) + 1];
        s_anbr[le][lane] = atom[(size_t)nbr * DD + lane];
    }

    // bond vectors (wave-local) into registers
    float bb[EPW][BOND_DIM];
#pragma unroll
    for (int j = 0; j < EPW; j++)
#pragma unroll
        for (int k = 0; k < BOND_DIM; k++) bb[j][k] = s_bond[wave * EPW + j][k];
    __syncthreads();

    // main loop: neighbor[f] = sum_d anbr[d] * relu(bias + sum_k bb[k]*Wk[d*64+f])
    float acc[EPW] = {};
    const float* wkp = ws + OFF_WKP;
#pragma unroll 2
    for (int d = 0; d < DD; d++) {
        float wkv[11];
#pragma unroll
        for (int k = 0; k < 11; k++) wkv[k] = wkp[(size_t)k * 4096 + d * DD + lane];
#pragma unroll
        for (int j = 0; j < EPW; j++) {
            float v = wkv[10];
#pragma unroll
            for (int k = 0; k < BOND_DIM; k++) v = fmaf(bb[j][k], wkv[k], v);
            v = fmaxf(v, 0.f);
            acc[j] = fmaf(s_anbr[wave * EPW + j][d], v, acc[j]);
        }
    }
#pragma unroll
    for (int j = 0; j < EPW; j++) s_nb[wave * EPW + j][lane] = acc[j];
    __syncthreads();

    // atend[f] = ab + sum_d attWT[d*64+f] * nb[d]   (coalesced attWT loads)
    const float ab = (ws + OFF_ATTB)[lane];
    const float* attWT = ws + OFF_ATTWT;
    float av[EPW];
#pragma unroll
    for (int j = 0; j < EPW; j++) av[j] = ab;
#pragma unroll 2
    for (int d = 0; d < DD; d++) {
        float w = attWT[d * DD + lane];
#pragma unroll
        for (int j = 0; j < EPW; j++) av[j] = fmaf(w, s_nb[wave * EPW + j][d], av[j]);
    }

    // score + exp + segment-sum atomics
    const float aw1 = alignW[lane];
    const float aw2 = alignW[64 + lane];
    const float alb = alignb[0];
#pragma unroll
    for (int j = 0; j < EPW; j++) {
        int le = wave * EPW + j;
        int tgt = s_tgt[le];
        float v = atom[(size_t)tgt * DD + lane] * aw1 + s_nb[le][lane] * aw2;
#pragma unroll
        for (int off = 32; off > 0; off >>= 1) v += __shfl_xor(v, off);
        float sc = v + alb;
        sc = sc > 0.f ? sc : 0.01f * sc;  // leaky_relu slope 0.01
        float ex = expf(sc);              // no max-shift: ratio identity, scores O(1)
        atomicAdd(&ctx[(size_t)tgt * DD + lane], ex * av[j]);
        if (lane == 0) atomicAdd(&denom[tgt], ex);
    }
}

// ---------- kernel 2: context finalize (elu) + GRU cell, transposed weights ----------
__global__ __launch_bounds__(192) void gru_kernel(
    const float* atom, const float* ws, const float* denom, const float* ctx,
    const float* bih, const float* bhh, float* out) {
    __shared__ float sctx[GA][DD];
    __shared__ float satom[GA][DD];
    __shared__ float sgi[GA][192];
    __shared__ float sgh[GA][192];
    const int a0 = blockIdx.x * GA;
    const int t = threadIdx.x;

    for (int idx = t; idx < GA * DD; idx += 192) {
        int a = idx >> 6, f = idx & 63;
        float c = ctx[(size_t)(a0 + a) * DD + f] / (denom[a0 + a] + EPS_SM);
        sctx[a][f] = c > 0.f ? c : expm1f(c);  // elu
        satom[a][f] = atom[(size_t)(a0 + a) * DD + f];
    }
    __syncthreads();

    const float* wiht = ws + OFF_WIHT;
    const float* whht = ws + OFF_WHHT;
    float gi[GA], gh[GA];
    const float bi = bih[t], bh = bhh[t];
#pragma unroll
    for (int a = 0; a < GA; a++) { gi[a] = bi; gh[a] = bh; }
#pragma unroll 4
    for (int d = 0; d < DD; d++) {
        float wi = wiht[d * 192 + t];   // coalesced across 192 threads
        float wh = whht[d * 192 + t];
#pragma unroll
        for (int a = 0; a < GA; a++) {
            gi[a] = fmaf(wi, sctx[a][d], gi[a]);
            gh[a] = fmaf(wh, satom[a][d], gh[a]);
        }
    }
#pragma unroll
    for (int a = 0; a < GA; a++) { sgi[a][t] = gi[a]; sgh[a][t] = gh[a]; }
    __syncthreads();

    for (int idx = t; idx < GA * DD; idx += 192) {
        int a = idx >> 6, f = idx & 63;
        float r = 1.f / (1.f + expf(-(sgi[a][f] + sgh[a][f])));
        float z = 1.f / (1.f + expf(-(sgi[a][64 + f] + sgh[a][64 + f])));
        float n = tanhf(sgi[a][128 + f] + r * sgh[a][128 + f]);
        out[(size_t)(a0 + a) * DD + f] = (1.f - z) * n + z * satom[a][f];
    }
}

extern "C" void kernel_launch(void* const* d_in, const int* in_sizes, int n_in,
                              void* d_out, int out_size, void* d_ws, size_t ws_size,
                              hipStream_t stream) {
    const float* atom   = (const float*)d_in[0];
    const int*   bidx   = (const int*)d_in[1];
    const float* bond   = (const float*)d_in[2];
    const float* enc_W  = (const float*)d_in[3];
    const float* enc_b  = (const float*)d_in[4];
    const float* bn1_g  = (const float*)d_in[5];
    const float* bn1_b  = (const float*)d_in[6];
    const float* bn1_m  = (const float*)d_in[7];
    const float* bn1_v  = (const float*)d_in[8];
    const float* alignW = (const float*)d_in[9];
    const float* alignb = (const float*)d_in[10];
    const float* att_W  = (const float*)d_in[11];
    const float* att_b  = (const float*)d_in[12];
    const float* bn2_g  = (const float*)d_in[13];
    const float* bn2_b  = (const float*)d_in[14];
    const float* bn2_m  = (const float*)d_in[15];
    const float* bn2_v  = (const float*)d_in[16];
    const float* gWih   = (const float*)d_in[17];
    const float* gWhh   = (const float*)d_in[18];
    const float* gbih   = (const float*)d_in[19];
    const float* gbhh   = (const float*)d_in[20];

    float* ws  = (float*)d_ws;
    float* out = (float*)d_out;   // reference output dtype is float32

    // zero denom + ctx accumulators (contiguous)
    hipMemsetAsync(ws + OFF_DENOM, 0, (size_t)(N_ATOM + (size_t)N_ATOM * DD) * 4, stream);

    fold_kernel<<<129, 256, 0, stream>>>(enc_W, enc_b, bn1_g, bn1_b, bn1_m, bn1_v,
                                         att_W, att_b, bn2_g, bn2_b, bn2_m, bn2_v,
                                         gWih, gWhh, ws);

    edge_kernel<<<N_EDGE / EPB, 256, 0, stream>>>(
        atom, bidx, bond, alignW, alignb, ws,
        ws + OFF_DENOM, ws + OFF_CTX);

    gru_kernel<<<N_ATOM / GA, 192, 0, stream>>>(atom, ws, ws + OFF_DENOM, ws + OFF_CTX,
                                                gbih, gbhh, out);
}